// Round 5
// baseline (92.939 us; speedup 1.0000x reference)
//
#include <hip/hip_runtime.h>
#include <stdint.h>

#define N_ROWS 65536
#define K_CODES 1024
#define D 64
#define OUT_ELEMS 4194304
#define LOSS_SCALE (1.25f / 4194304.0f)
#define ROWS_PER_BLOCK 256
#define GRID_DIST (N_ROWS / ROWS_PER_BLOCK)  // 256 blocks = 1/CU

typedef short short8 __attribute__((ext_vector_type(8)));
typedef float f32x4 __attribute__((ext_vector_type(4)));

__device__ __forceinline__ unsigned short f2bf(float f) {
    unsigned int u = __float_as_uint(f);
    return (unsigned short)((u + 0x7fffu + ((u >> 16) & 1u)) >> 16);  // RNE
}

#define GLOAD_LDS16(g, l)                                                          \
    __builtin_amdgcn_global_load_lds((const __attribute__((address_space(1))) void*)(g), \
                                     (__attribute__((address_space(3))) void*)(l), 16, 0, 0)

// Prep: ebm2 = bf16(-2*emb) (MFMA acc = e2 - 2*z.e directly); e2 = ||e_k||^2 fp32-exact.
#define ECH (K_CODES * D / 8)  // 8192
__global__ __launch_bounds__(256) void prep_kernel(const float* __restrict__ emb,
                                                   unsigned short* __restrict__ ebm2,
                                                   float* __restrict__ e2) {
    int t = blockIdx.x * 256 + threadIdx.x;
    if (t < ECH) {
        const float4* s = (const float4*)emb;
        float4 a = s[2 * t], b = s[2 * t + 1];
        uint4 o;
        o.x = f2bf(-2.f * a.x) | ((unsigned int)f2bf(-2.f * a.y) << 16);
        o.y = f2bf(-2.f * a.z) | ((unsigned int)f2bf(-2.f * a.w) << 16);
        o.z = f2bf(-2.f * b.x) | ((unsigned int)f2bf(-2.f * b.y) << 16);
        o.w = f2bf(-2.f * b.z) | ((unsigned int)f2bf(-2.f * b.w) << 16);
        ((uint4*)ebm2)[t] = o;
    } else if (t < ECH + K_CODES) {
        int k = t - ECH;
        const float4* e4 = (const float4*)emb;
        float s = 0.f;
#pragma unroll
        for (int i = 0; i < 16; i++) {
            float4 v = e4[k * 16 + i];
            s += v.x * v.x + v.y * v.y + v.z * v.z + v.w * v.w;
        }
        e2[k] = s;
    }
}

// Fused MFMA distance + argmin + quantize-write + loss.
// 1 block/CU; each wave owns 64 z-rows (4 MFMA row-sets) -> each LDS A-frag
// feeds 8 MFMAs (2x the R4 reuse). Loss = dist_best(MFMA) + ||z||^2(fp32),
// so the epilogue never re-reads z; it only gather-writes emb rows per-wave
// (indices broadcast via shuffles, no barrier).
__global__ __launch_bounds__(256) void dist_fused_kernel(
        const float* __restrict__ z, const unsigned short* __restrict__ ebm2,
        const float* __restrict__ e2, const float* __restrict__ emb,
        float* __restrict__ out, float* __restrict__ partials) {
    __shared__ __align__(16) char smem[65536];  // 2x32KB staging; ps overlay at end
    const int tid = threadIdx.x;
    const int wave = tid >> 6, lane = tid & 63;
    const int n = lane & 15, q = lane >> 4, nb = n & 7;
    const int wave_row0 = blockIdx.x * ROWS_PER_BLOCK + wave * 64;

    // Stage one 256-code chunk (2048 16B slots) into buf[c&1]; XOR-swizzled source
    // so ds_read_b128 A-frags are 2-way (free) instead of 16-way conflicted.
    auto stage = [&](int c) {
        const int bufoff = (c & 1) << 15;
        const uint4* gsrc = (const uint4*)ebm2;
#pragma unroll
        for (int r = 0; r < 8; r++) {
            int S = c * 2048 + r * 256 + tid;
            int P = (S & ~7) | ((S & 7) ^ ((S >> 3) & 7));
            char* l = smem + bufoff + (r * 256 + (tid & ~63)) * 16;  // wave-uniform base
            GLOAD_LDS16(gsrc + P, l);
        }
    };
    stage(0);  // issue before z loads so staging overlaps the HBM read burst

    // z: 4 row-sets x 16 rows; lane holds rows (rs,n), k-slices [q*8,+8) and [32+q*8,+8).
    // fp32 ||z||^2 partials computed here (exact); bf16 pack for MFMA B-frags.
    short8 b[4][2];
    float z2p[4];
#pragma unroll
    for (int rs = 0; rs < 4; rs++) {
        const float* zr = z + (size_t)(wave_row0 + rs * 16 + n) * D + q * 8;
        float4 f0 = *(const float4*)(zr);
        float4 f1 = *(const float4*)(zr + 4);
        float4 f2 = *(const float4*)(zr + 32);
        float4 f3 = *(const float4*)(zr + 36);
        z2p[rs] = f0.x*f0.x + f0.y*f0.y + f0.z*f0.z + f0.w*f0.w
                + f1.x*f1.x + f1.y*f1.y + f1.z*f1.z + f1.w*f1.w
                + f2.x*f2.x + f2.y*f2.y + f2.z*f2.z + f2.w*f2.w
                + f3.x*f3.x + f3.y*f3.y + f3.z*f3.z + f3.w*f3.w;
        short8 lo, hi;
        lo[0] = f2bf(f0.x); lo[1] = f2bf(f0.y); lo[2] = f2bf(f0.z); lo[3] = f2bf(f0.w);
        lo[4] = f2bf(f1.x); lo[5] = f2bf(f1.y); lo[6] = f2bf(f1.z); lo[7] = f2bf(f1.w);
        hi[0] = f2bf(f2.x); hi[1] = f2bf(f2.y); hi[2] = f2bf(f2.z); hi[3] = f2bf(f2.w);
        hi[4] = f2bf(f3.x); hi[5] = f2bf(f3.y); hi[6] = f2bf(f3.z); hi[7] = f2bf(f3.w);
        b[rs][0] = lo; b[rs][1] = hi;
    }

    // e2 prefetch slots (global, L2-hot, depth 2) + swizzled LDS read offsets.
    f32x4 Ea = *(const f32x4*)(e2 + q * 4);
    f32x4 Eb = *(const f32x4*)(e2 + 16 + q * 4);
    const int base0 = n * 128 + ((q ^ nb) << 4);
    const int base1 = n * 128 + (((4 | q) ^ nb) << 4);

    float bestd[4] = {INFINITY, INFINITY, INFINITY, INFINITY};
    int bestk[4] = {0, 0, 0, 0};

    __syncthreads();  // staging chunk 0 landed
    for (int c = 0; c < 4; c++) {
        if (c < 3) stage(c + 1);  // async into other buffer, overlaps compute
        const char* buf = smem + ((c & 1) << 15);
#pragma unroll
        for (int tl = 0; tl < 16; tl++) {
            const int t = c * 16 + tl;
            short8 a0 = *(const short8*)(buf + tl * 2048 + base0);
            short8 a1 = *(const short8*)(buf + tl * 2048 + base1);
            f32x4 E = (tl & 1) ? Eb : Ea;
            f32x4 acc[4];
#pragma unroll
            for (int rs = 0; rs < 4; rs++) {
                f32x4 a = E;  // acc init = ||e||^2
                a = __builtin_amdgcn_mfma_f32_16x16x32_bf16(a0, b[rs][0], a, 0, 0, 0);
                a = __builtin_amdgcn_mfma_f32_16x16x32_bf16(a1, b[rs][1], a, 0, 0, 0);
                acc[rs] = a;
            }
            int tp = (t + 2 > 63) ? 63 : (t + 2);
            f32x4 En = *(const f32x4*)(e2 + tp * 16 + q * 4);
            if (tl & 1) Eb = En; else Ea = En;
#pragma unroll
            for (int rs = 0; rs < 4; rs++)
#pragma unroll
                for (int r = 0; r < 4; r++) {  // per-lane codes ascend: strict < = first-min
                    float d = acc[rs][r];
                    if (d < bestd[rs]) { bestd[rs] = d; bestk[rs] = t * 16 + q * 4 + r; }
                }
        }
        __syncthreads();  // chunk reads done; drains next stage too
    }

    // Cross-quad argmin (u64 monotone key -> numpy tie semantics) + loss terms.
    float lossl = 0.f;
    int bidx[4];
#pragma unroll
    for (int rs = 0; rs < 4; rs++) {
        unsigned int db = __float_as_uint(bestd[rs]);
        db = (db & 0x80000000u) ? ~db : (db | 0x80000000u);
        unsigned long long key = ((unsigned long long)db << 32) | (unsigned int)bestk[rs];
        unsigned long long o = __shfl_xor(key, 16, 64); key = o < key ? o : key;
        o = __shfl_xor(key, 32, 64); key = o < key ? o : key;  // all lanes hold result
        bidx[rs] = (int)(key & 0xFFFFFFFFu);
        unsigned int eu = (unsigned int)(key >> 32);
        float bd = __uint_as_float((eu & 0x80000000u) ? (eu & 0x7FFFFFFFu) : ~eu);
        float z2r = z2p[rs];
        z2r += __shfl_xor(z2r, 16, 64);
        z2r += __shfl_xor(z2r, 32, 64);
        lossl += bd + z2r;  // ||q - z||^2 for row (rs, n); replicated 4x across quads
    }

    // Epilogue: per-wave gather-write of quantized rows (no barrier, no z re-read).
    const float4* emb4 = (const float4*)emb;
    float4* o4 = (float4*)out + (size_t)wave_row0 * 16;
#pragma unroll
    for (int it = 0; it < 16; it++) {
        int k = __shfl(bidx[it >> 2], (it * 4 + q) & 15, 64);  // idx of row it*4+q
        o4[it * 64 + lane] = emb4[k * 16 + n];
    }

    // Loss: sum over all 64 lanes counts each row 4x -> scale 0.25 at block level.
#pragma unroll
    for (int off = 32; off > 0; off >>= 1)
        lossl += __shfl_down(lossl, off, 64);
    float* ps = (float*)smem;  // staging buffers done
    if (lane == 0) ps[wave] = lossl;
    __syncthreads();
    if (tid == 0) partials[blockIdx.x] = 0.25f * (ps[0] + ps[1] + ps[2] + ps[3]);
}

// Single block: sum 256 partials -> loss (no atomics anywhere).
__global__ __launch_bounds__(256) void loss_kernel(const float* __restrict__ partials,
                                                   float* __restrict__ loss) {
    float s = partials[threadIdx.x];
#pragma unroll
    for (int off = 32; off > 0; off >>= 1)
        s += __shfl_down(s, off, 64);
    __shared__ float ps[4];
    int wave = threadIdx.x >> 6, lane = threadIdx.x & 63;
    if (lane == 0) ps[wave] = s;
    __syncthreads();
    if (threadIdx.x == 0) loss[0] = (ps[0] + ps[1] + ps[2] + ps[3]) * LOSS_SCALE;
}

extern "C" void kernel_launch(void* const* d_in, const int* in_sizes, int n_in,
                              void* d_out, int out_size, void* d_ws, size_t ws_size,
                              hipStream_t stream) {
    const float* z = (const float*)d_in[0];
    const float* emb = (const float*)d_in[1];
    float* out = (float*)d_out;
    float* loss = out + OUT_ELEMS;

    char* ws = (char*)d_ws;
    float* e2 = (float*)ws;                                       // 4 KiB
    unsigned short* ebm2 = (unsigned short*)(ws + 4096);          // 128 KiB
    float* partials = (float*)(ws + 4096 + 131072 + 8192);        // 1 KiB (8K pad)

    prep_kernel<<<(ECH + K_CODES + 255) / 256, 256, 0, stream>>>(emb, ebm2, e2);
    dist_fused_kernel<<<GRID_DIST, 256, 0, stream>>>(z, ebm2, e2, emb, out, partials);
    loss_kernel<<<1, 256, 0, stream>>>(partials, loss);
}